// Round 9
// baseline (869.145 us; speedup 1.0000x reference)
//
#include <hip/hip_runtime.h>
#include <hip/hip_cooperative_groups.h>
#include <cstddef>

namespace cg = cooperative_groups;

#define NSAMP 16
#define HW 409600
#define CPRED 6
#define EPS 1e-6
#define NB1 2048       // top-11 bits
#define NB3 1024       // low-10 bits
#define L1SHIFT 21
#define GRID 1024
#define BPS 64         // blocks per sample
#define F4PB 1600      // float4 per block (6400 elements)

struct Shm {
    unsigned h[NB1];        // 8 KB: hist copy / scan bins / double scratch
    unsigned chunkSum[256]; // 1 KB
};

__device__ __forceinline__ unsigned sortkey(float f) {
    unsigned b = __float_as_uint(f);
    return (b & 0x80000000u) ? ~b : (b | 0x80000000u);   // larger float -> larger key
}
__device__ __forceinline__ float inv_sortkey(unsigned k) {
    unsigned b = (k & 0x80000000u) ? (k ^ 0x80000000u) : ~k;
    return __uint_as_float(b);
}
__device__ __forceinline__ float sigmoidf(float x) {
    return 1.0f / (1.0f + __expf(-x));
}

__global__ void k_zero(unsigned* __restrict__ p, unsigned n) {
    unsigned i = blockIdx.x * 256 + threadIdx.x;
    if (i < n) p[i] = 0;
}

// ---------------- phase bodies (shared by coop kernel and fallback chain) ----

// P1: stream pred0/t0/eff -> pos/negc (device atomics) + level-1 LDS hist.
__device__ void phase1(Shm* s, int b,
                       const float* preds, const float* targets, const float* eff,
                       unsigned* hist, unsigned* pos, unsigned* negc) {
    const int n = b >> 6, sub = b & 63;
    const int tid = threadIdx.x, lane = tid & 63;
    for (int i = tid; i < NB1; i += 256) s->h[i] = 0;
    __syncthreads();
    const float4* p04 = (const float4*)(preds + (size_t)n * CPRED * HW);
    const float4* t04 = (const float4*)(targets + (size_t)n * 2 * HW);
    const float4* e4  = (const float4*)(eff + (size_t)n * HW);
    const int base4 = sub * F4PB;
    unsigned lp = 0, ln = 0;
#pragma unroll
    for (int k = 0; k < 7; k++) {
        if (k < 6 || tid < 64) {            // 1600 f4 = 6*256 + 64
            int i = base4 + k * 256 + tid;
            float4 p = p04[i], t = t04[i], e = e4[i];
            float pa[4] = {p.x, p.y, p.z, p.w};
            float ta[4] = {t.x, t.y, t.z, t.w};
            float ea[4] = {e.x, e.y, e.z, e.w};
#pragma unroll
            for (int j = 0; j < 4; j++) {
                lp += (ta[j] > 0.5f && ea[j] > 0.5f) ? 1u : 0u;
                if (ta[j] <= 0.5f) {
                    ln++;
                    atomicAdd(&s->h[sortkey(pa[j]) >> L1SHIFT], 1u);
                }
            }
        }
    }
    for (int o = 32; o; o >>= 1) {
        lp += __shfl_down(lp, o, 64);
        ln += __shfl_down(ln, o, 64);
    }
    if (lane == 0) {
        atomicAdd(&pos[n], lp);
        atomicAdd(&negc[n], ln);
    }
    __syncthreads();
    unsigned* gh = hist + (size_t)n * NB1;
    for (int i = tid; i < NB1; i += 256) {
        unsigned v = s->h[i];
        if (v) atomicAdd(&gh[i], v);
    }
}

// P2: scan level-1 -> b1, rem1, fb; zero gh for level 2. One block per sample.
__device__ void phase2(Shm* s, int n, unsigned* hist,
                       const unsigned* pos, const unsigned* negc,
                       unsigned* b1, unsigned* rem1, unsigned* fb) {
    const int tid = threadIdx.x;
    unsigned* gh = hist + (size_t)n * NB1;
    for (int i = tid; i < NB1; i += 256) s->h[i] = gh[i];
    __syncthreads();
    unsigned cs = 0;
#pragma unroll
    for (int j = 0; j < 8; j++) cs += s->h[tid * 8 + j];
    s->chunkSum[tid] = cs;
    __syncthreads();
    if (tid == 0) {
        const unsigned P = pos[n], NC = negc[n];
        const unsigned nn = (P * 3u < NC) ? P * 3u : NC;
        if (P == 0 || nn == 0) {
            b1[n] = 0xFFFFFFFFu; rem1[n] = 0; fb[n] = 1u;
        } else {
            fb[n] = 0u;
            unsigned cum = 0; int c;
            for (c = 255;; c--) { if (cum + s->chunkSum[c] >= nn) break; cum += s->chunkSum[c]; }
            int bb;
            for (bb = c * 8 + 7;; bb--) { unsigned hv = s->h[bb]; if (cum + hv >= nn) break; cum += hv; }
            b1[n] = (unsigned)bb; rem1[n] = nn - cum;
        }
    }
    __syncthreads();
    for (int i = tid; i < NB1; i += 256) gh[i] = 0;
}

// P3: level-2 histogram (re-read pred0/t0; L3-hot after P1).
__device__ void phase3(Shm* s, int b,
                       const float* preds, const float* targets,
                       const unsigned* b1, unsigned* hist) {
    const int n = b >> 6, sub = b & 63;
    const int tid = threadIdx.x;
    const unsigned B1 = b1[n];
    if (B1 == 0xFFFFFFFFu) return;
    for (int i = tid; i < NB1; i += 256) s->h[i] = 0;
    __syncthreads();
    const float4* p04 = (const float4*)(preds + (size_t)n * CPRED * HW);
    const float4* t04 = (const float4*)(targets + (size_t)n * 2 * HW);
    const int base4 = sub * F4PB;
#pragma unroll
    for (int k = 0; k < 7; k++) {
        if (k < 6 || tid < 64) {
            int i = base4 + k * 256 + tid;
            float4 p = p04[i], t = t04[i];
            float pa[4] = {p.x, p.y, p.z, p.w};
            float ta[4] = {t.x, t.y, t.z, t.w};
#pragma unroll
            for (int j = 0; j < 4; j++) {
                if (ta[j] <= 0.5f) {
                    unsigned key = sortkey(pa[j]);
                    if ((key >> L1SHIFT) == B1)
                        atomicAdd(&s->h[(key >> 10) & 0x7FFu], 1u);
                }
            }
        }
    }
    __syncthreads();
    unsigned* gh = hist + (size_t)n * NB1;
    for (int i = tid; i < NB1; i += 256) {
        unsigned v = s->h[i];
        if (v) atomicAdd(&gh[i], v);
    }
}

// P4: scan level-2 -> b2, rem2; zero gh for level 3.
__device__ void phase4(Shm* s, int n, unsigned* hist,
                       const unsigned* fb, const unsigned* rem1,
                       unsigned* b2, unsigned* rem2) {
    const int tid = threadIdx.x;
    unsigned* gh = hist + (size_t)n * NB1;
    for (int i = tid; i < NB1; i += 256) s->h[i] = gh[i];
    __syncthreads();
    unsigned cs = 0;
#pragma unroll
    for (int j = 0; j < 8; j++) cs += s->h[tid * 8 + j];
    s->chunkSum[tid] = cs;
    __syncthreads();
    if (tid == 0) {
        if (fb[n]) { b2[n] = 0; rem2[n] = 0; }
        else {
            const unsigned r = rem1[n];
            unsigned cum = 0; int c;
            for (c = 255;; c--) { if (cum + s->chunkSum[c] >= r) break; cum += s->chunkSum[c]; }
            int bb;
            for (bb = c * 8 + 7;; bb--) { unsigned hv = s->h[bb]; if (cum + hv >= r) break; cum += hv; }
            b2[n] = (unsigned)bb; rem2[n] = r - cum;
        }
    }
    __syncthreads();
    for (int i = tid; i < NB1; i += 256) gh[i] = 0;
}

// P5: level-3 histogram (low 10 bits).
__device__ void phase5(Shm* s, int b,
                       const float* preds, const float* targets,
                       const unsigned* b1, const unsigned* b2, unsigned* hist) {
    const int n = b >> 6, sub = b & 63;
    const int tid = threadIdx.x;
    const unsigned B1 = b1[n];
    if (B1 == 0xFFFFFFFFu) return;
    const unsigned prefix = (B1 << 11) | b2[n];
    for (int i = tid; i < NB3; i += 256) s->h[i] = 0;
    __syncthreads();
    const float4* p04 = (const float4*)(preds + (size_t)n * CPRED * HW);
    const float4* t04 = (const float4*)(targets + (size_t)n * 2 * HW);
    const int base4 = sub * F4PB;
#pragma unroll
    for (int k = 0; k < 7; k++) {
        if (k < 6 || tid < 64) {
            int i = base4 + k * 256 + tid;
            float4 p = p04[i], t = t04[i];
            float pa[4] = {p.x, p.y, p.z, p.w};
            float ta[4] = {t.x, t.y, t.z, t.w};
#pragma unroll
            for (int j = 0; j < 4; j++) {
                if (ta[j] <= 0.5f) {
                    unsigned key = sortkey(pa[j]);
                    if ((key >> 10) == prefix)
                        atomicAdd(&s->h[key & 0x3FFu], 1u);
                }
            }
        }
    }
    __syncthreads();
    unsigned* gh = hist + (size_t)n * NB1;
    for (int i = tid; i < NB3; i += 256) {
        unsigned v = s->h[i];
        if (v) atomicAdd(&gh[i], v);
    }
}

// P6: scan level-3 -> thr.
__device__ void phase6(Shm* s, int n, const unsigned* hist,
                       const unsigned* fb, const unsigned* b1, const unsigned* b2,
                       const unsigned* rem2, float* thr) {
    const int tid = threadIdx.x;
    const unsigned* gh = hist + (size_t)n * NB1;
    for (int i = tid; i < NB3; i += 256) s->h[i] = gh[i];
    __syncthreads();
    unsigned cs = 0;
#pragma unroll
    for (int j = 0; j < 4; j++) cs += s->h[tid * 4 + j];
    s->chunkSum[tid] = cs;
    __syncthreads();
    if (tid == 0) {
        if (fb[n]) thr[n] = -INFINITY;
        else {
            const unsigned r = rem2[n];
            unsigned cum = 0; int c;
            for (c = 255;; c--) { if (cum + s->chunkSum[c] >= r) break; cum += s->chunkSum[c]; }
            int bb;
            for (bb = c * 4 + 3;; bb--) { unsigned hv = s->h[bb]; if (cum + hv >= r) break; cum += hv; }
            thr[n] = inv_sortkey((b1[n] << L1SHIFT) | (b2[n] << 10) | (unsigned)bb);
        }
    }
}

// P7: dice partial sums, one plain 6-double store per block.
__device__ void phase7(Shm* s, int b,
                       const float* preds, const float* targets, const float* eff,
                       const float* thr, const unsigned* fb, double* partials) {
    const int n = b >> 6, sub = b & 63;
    const int tid = threadIdx.x, wave = tid >> 6, lane = tid & 63;
    const float* pr0 = preds + (size_t)n * CPRED * HW;
    const float* tg0 = targets + (size_t)n * 2 * HW;
    const float4* p04 = (const float4*)pr0;
    const float4* p14 = (const float4*)(pr0 + HW);
    const float4* t04 = (const float4*)tg0;
    const float4* t14 = (const float4*)(tg0 + HW);
    const float4* e4  = (const float4*)(eff + (size_t)n * HW);
    const int base4 = sub * F4PB;
    const float th = thr[n];
    const bool fallback = (fb[n] != 0);
    float sPG = 0.f, sP2 = 0.f, sG2 = 0.f, sPGk = 0.f, sP2k = 0.f, sG2k = 0.f;
#pragma unroll
    for (int k = 0; k < 7; k++) {
        if (k < 6 || tid < 64) {
            int i = base4 + k * 256 + tid;
            float4 a = p04[i], c4 = p14[i], t = t04[i], u = t14[i], e = e4[i];
            float pa[4] = {a.x, a.y, a.z, a.w};
            float pb[4] = {c4.x, c4.y, c4.z, c4.w};
            float ta[4] = {t.x, t.y, t.z, t.w};
            float ua[4] = {u.x, u.y, u.z, u.w};
            float ea[4] = {e.x, e.y, e.z, e.w};
#pragma unroll
            for (int j = 0; j < 4; j++) {
                float pt = sigmoidf(pa[j]);
                float pk = sigmoidf(pb[j]);
                float tbt = (ta[j] > 0.5f) ? 1.f : 0.f;
                float tbk = (ua[j] > 0.5f) ? 1.f : 0.f;
                float m;
                if (fallback) m = ea[j];
                else m = (((pa[j] >= th) || (ta[j] > 0.5f)) && (ea[j] > 0.5f)) ? 1.f : 0.f;
                float Pm = pt * m, Tm = tbt * m;
                sPG += Pm * Tm; sP2 += Pm * Pm; sG2 += Tm * Tm;
                float mk = (pt > 0.5f && ea[j] > 0.5f) ? 1.f : 0.f;
                float Pk = pk * mk, Tk = tbk * mk;
                sPGk += Pk * Tk; sP2k += Pk * Pk; sG2k += Tk * Tk;
            }
        }
    }
    for (int o = 32; o; o >>= 1) {
        sPG  += __shfl_down(sPG, o, 64);
        sP2  += __shfl_down(sP2, o, 64);
        sG2  += __shfl_down(sG2, o, 64);
        sPGk += __shfl_down(sPGk, o, 64);
        sP2k += __shfl_down(sP2k, o, 64);
        sG2k += __shfl_down(sG2k, o, 64);
    }
    double* dws = (double*)s->h;   // 24 doubles
    __syncthreads();
    if (lane == 0) {
        dws[wave * 6 + 0] = sPG;  dws[wave * 6 + 1] = sP2;  dws[wave * 6 + 2] = sG2;
        dws[wave * 6 + 3] = sPGk; dws[wave * 6 + 4] = sP2k; dws[wave * 6 + 5] = sG2k;
    }
    __syncthreads();
    if (tid < 6) {
        double v = dws[tid] + dws[6 + tid] + dws[12 + tid] + dws[18 + tid];
        partials[(size_t)b * 6 + tid] = v;
    }
}

// P8: reduce partials, emit 32 outputs (single block).
__device__ void phase8(Shm* s, const double* partials, float* out) {
    double* ssum = (double*)s->h;
    const int t = threadIdx.x;
    if (t < 96) {
        const int n = t / 6, c = t % 6;
        double a = 0.0;
        for (int sb = 0; sb < BPS; sb++) a += partials[((size_t)(n * BPS + sb)) * 6 + c];
        ssum[t] = a;
    }
    __syncthreads();
    if (t < NSAMP) {
        const double* sv = &ssum[t * 6];
        out[t]         = (float)(1.0 - 2.0 * sv[0] / (sv[1] + sv[2] + EPS));
        out[NSAMP + t] = (float)(1.0 - 2.0 * sv[3] / (sv[4] + sv[5] + EPS));
    }
}

// ---------------- cooperative fused kernel ----------------
__global__ __launch_bounds__(256, 4)
void k_mega(const float* __restrict__ preds, const float* __restrict__ targets,
            const float* __restrict__ eff,
            unsigned* __restrict__ hist, unsigned* __restrict__ pos,
            unsigned* __restrict__ negc, unsigned* __restrict__ b1,
            unsigned* __restrict__ b2, unsigned* __restrict__ rem1,
            unsigned* __restrict__ rem2, unsigned* __restrict__ fb,
            float* __restrict__ thr, double* __restrict__ partials,
            float* __restrict__ out) {
    cg::grid_group grid = cg::this_grid();
    __shared__ Shm s;
    const int b = blockIdx.x;
    phase1(&s, b, preds, targets, eff, hist, pos, negc);
    grid.sync();
    if ((b & 63) == 0) phase2(&s, b >> 6, hist, pos, negc, b1, rem1, fb);
    grid.sync();
    phase3(&s, b, preds, targets, b1, hist);
    grid.sync();
    if ((b & 63) == 0) phase4(&s, b >> 6, hist, fb, rem1, b2, rem2);
    grid.sync();
    phase5(&s, b, preds, targets, b1, b2, hist);
    grid.sync();
    if ((b & 63) == 0) phase6(&s, b >> 6, hist, fb, b1, b2, rem2, thr);
    grid.sync();
    phase7(&s, b, preds, targets, eff, thr, fb, partials);
    grid.sync();
    if (b == 0) phase8(&s, partials, out);
}

// ---------------- fallback chain (identical math, kernel-boundary sync) -----
__global__ void k_p1(const float* preds, const float* targets, const float* eff,
                     unsigned* hist, unsigned* pos, unsigned* negc) {
    __shared__ Shm s; phase1(&s, blockIdx.x, preds, targets, eff, hist, pos, negc);
}
__global__ void k_p2(unsigned* hist, const unsigned* pos, const unsigned* negc,
                     unsigned* b1, unsigned* rem1, unsigned* fb) {
    __shared__ Shm s; phase2(&s, blockIdx.x, hist, pos, negc, b1, rem1, fb);
}
__global__ void k_p3(const float* preds, const float* targets,
                     const unsigned* b1, unsigned* hist) {
    __shared__ Shm s; phase3(&s, blockIdx.x, preds, targets, b1, hist);
}
__global__ void k_p4(unsigned* hist, const unsigned* fb, const unsigned* rem1,
                     unsigned* b2, unsigned* rem2) {
    __shared__ Shm s; phase4(&s, blockIdx.x, hist, fb, rem1, b2, rem2);
}
__global__ void k_p5(const float* preds, const float* targets,
                     const unsigned* b1, const unsigned* b2, unsigned* hist) {
    __shared__ Shm s; phase5(&s, blockIdx.x, preds, targets, b1, b2, hist);
}
__global__ void k_p6(const unsigned* hist, const unsigned* fb, const unsigned* b1,
                     const unsigned* b2, const unsigned* rem2, float* thr) {
    __shared__ Shm s; phase6(&s, blockIdx.x, hist, fb, b1, b2, rem2, thr);
}
__global__ void k_p7(const float* preds, const float* targets, const float* eff,
                     const float* thr, const unsigned* fb, double* partials) {
    __shared__ Shm s; phase7(&s, blockIdx.x, preds, targets, eff, thr, fb, partials);
}
__global__ void k_p8(const double* partials, float* out) {
    __shared__ Shm s; phase8(&s, partials, out);
}

extern "C" void kernel_launch(void* const* d_in, const int* in_sizes, int n_in,
                              void* d_out, int out_size, void* d_ws, size_t ws_size,
                              hipStream_t stream) {
    const float* preds = (const float*)d_in[0];
    const float* targets = (const float*)d_in[1];
    const float* eff = (const float*)d_in[2];
    float* out = (float*)d_out;

    char* ws = (char*)d_ws;
    unsigned* hist = (unsigned*)ws;                  // 131072 B
    unsigned* pos  = (unsigned*)(ws + 131072);       // 16 u32
    unsigned* negc = pos + NSAMP;                    // ends at u32 index 32800
    unsigned* b1   = negc + NSAMP;
    unsigned* b2   = b1 + NSAMP;
    unsigned* rem1 = b2 + NSAMP;
    unsigned* rem2 = rem1 + NSAMP;
    unsigned* fb   = rem2 + NSAMP;
    float*    thr  = (float*)(fb + NSAMP);
    double* partials = (double*)(ws + 131072 + 512); // 8-aligned; 1024*6*8 = 49152 B

    // zero hist + pos + negc (contiguous); everything else written unconditionally
    k_zero<<<(32800 + 255) / 256, 256, 0, stream>>>(hist, 32800);

    void* args[] = {(void*)&preds, (void*)&targets, (void*)&eff,
                    (void*)&hist, (void*)&pos, (void*)&negc,
                    (void*)&b1, (void*)&b2, (void*)&rem1, (void*)&rem2,
                    (void*)&fb, (void*)&thr, (void*)&partials, (void*)&out};
    hipError_t e = hipLaunchCooperativeKernel((void*)k_mega, dim3(GRID), dim3(256),
                                              args, 0, stream);
    if (e != hipSuccess) {
        // fallback: same phases as discrete kernels (kernel-boundary coherence)
        k_p1<<<GRID, 256, 0, stream>>>(preds, targets, eff, hist, pos, negc);
        k_p2<<<NSAMP, 256, 0, stream>>>(hist, pos, negc, b1, rem1, fb);
        k_p3<<<GRID, 256, 0, stream>>>(preds, targets, b1, hist);
        k_p4<<<NSAMP, 256, 0, stream>>>(hist, fb, rem1, b2, rem2);
        k_p5<<<GRID, 256, 0, stream>>>(preds, targets, b1, b2, hist);
        k_p6<<<NSAMP, 256, 0, stream>>>(hist, fb, b1, b2, rem2, thr);
        k_p7<<<GRID, 256, 0, stream>>>(preds, targets, eff, thr, fb, partials);
        k_p8<<<1, 256, 0, stream>>>(partials, out);
    }
}

// Round 10
// 139.728 us; speedup vs baseline: 6.2203x; 6.2203x over previous
//
#include <hip/hip_runtime.h>
#include <cstddef>

#define NSAMP 16
#define HW 409600
#define CPRED 6
#define EPS 1e-6
#define NB1 2048      // top-11 bits
#define NB2 2048      // next-11 bits
#define NB3 1024      // low-10 bits
#define L1SHIFT 21
#define BPSH 50       // blocks/sample, stats
#define BPSC 25       // blocks/sample, refine
#define BPSD 100      // blocks/sample, dice
#define SENT 0xFFFFFFFFu

__device__ __forceinline__ unsigned sortkey(float f) {
    unsigned b = __float_as_uint(f);
    return (b & 0x80000000u) ? ~b : (b | 0x80000000u);   // larger float -> larger key
}
__device__ __forceinline__ float inv_sortkey(unsigned k) {
    unsigned b = (k & 0x80000000u) ? (k ^ 0x80000000u) : ~k;
    return __uint_as_float(b);
}
__device__ __forceinline__ float sigmoidf(float x) {
    return 1.0f / (1.0f + __expf(-x));
}

__global__ void k_zero(uint4* __restrict__ p, unsigned n4) {
    unsigned i = blockIdx.x * 256 + threadIdx.x;
    if (i < n4) p[i] = uint4{0, 0, 0, 0};
}

// Pass 1 (proven in R5): pos/neg counts + level-1 LDS hist + LDS-staged key
// compaction; one global atomicAdd per block for the key base.
__global__ void k_stats(const float* __restrict__ preds,
                        const float* __restrict__ targets,
                        const float* __restrict__ eff,
                        unsigned* __restrict__ hist1,
                        unsigned* __restrict__ pos,
                        unsigned* __restrict__ negc,
                        unsigned* __restrict__ nkeys,
                        unsigned* __restrict__ keys) {
    const int n = blockIdx.y;
    const float4* p4 = (const float4*)(preds + (size_t)n * CPRED * HW);
    const float4* t4 = (const float4*)(targets + (size_t)n * 2 * HW);
    const float4* e4 = (const float4*)(eff + (size_t)n * HW);
    __shared__ unsigned h[4][NB1];     // 32 KB, per-wave copies
    __shared__ unsigned kbuf[4][2048]; // 32 KB (each wave owns exactly 2048 elems)
    __shared__ unsigned kcnt[4];
    __shared__ unsigned kbase;
    for (int i = threadIdx.x; i < 4 * NB1; i += 256) ((unsigned*)h)[i] = 0;
    __syncthreads();
    const int wave = threadIdx.x >> 6;
    const int lane = threadIdx.x & 63;
    const unsigned long long lmask = (1ull << lane) - 1ull;
    unsigned lp = 0, run = 0;
    const int base = blockIdx.x * 2048;   // float4 units; 8192 floats/block
#pragma unroll
    for (int k = 0; k < 8; k++) {
        int i = base + k * 256 + threadIdx.x;
        float4 p = p4[i], t = t4[i], e = e4[i];
        float pa[4] = {p.x, p.y, p.z, p.w};
        float ta[4] = {t.x, t.y, t.z, t.w};
        float ea[4] = {e.x, e.y, e.z, e.w};
#pragma unroll
        for (int j = 0; j < 4; j++) {
            lp += (ta[j] > 0.5f && ea[j] > 0.5f) ? 1u : 0u;
            const bool isneg = (ta[j] <= 0.5f);
            unsigned long long bm = __ballot(isneg);
            if (isneg) {
                unsigned key = sortkey(pa[j]);
                atomicAdd(&h[wave][key >> L1SHIFT], 1u);
                int rank = __popcll(bm & lmask);
                kbuf[wave][run + rank] = key;
            }
            run += (unsigned)__popcll(bm);
        }
    }
    for (int o = 32; o; o >>= 1) lp += __shfl_down(lp, o, 64);
    if (lane == 0) {
        atomicAdd(&pos[n], lp);
        atomicAdd(&negc[n], run);
        kcnt[wave] = run;
    }
    __syncthreads();
    unsigned* gh = hist1 + (size_t)n * NB1;
    for (int b = threadIdx.x; b < NB1; b += 256) {
        unsigned s = h[0][b] + h[1][b] + h[2][b] + h[3][b];
        if (s) atomicAdd(&gh[b], s);
    }
    if (threadIdx.x == 0)
        kbase = atomicAdd(&nkeys[n], kcnt[0] + kcnt[1] + kcnt[2] + kcnt[3]);
    __syncthreads();
    unsigned off = kbase;
    for (int w = 0; w < wave; w++) off += kcnt[w];
    unsigned* kout = keys + (size_t)n * HW;
    const unsigned cnt = kcnt[wave];
    for (unsigned i = lane; i < cnt; i += 64) kout[off + i] = kbuf[wave][i];
}

// Pass 2: every block recomputes scan1 from hist1 (redundant, ~1us, replaces a
// kernel+launch), then histograms level-2 bits of matching keys into hist2.
// Block x==0 publishes b1/rem1/fb for later kernels.
__global__ void k_ref2(const unsigned* __restrict__ keys,
                       const unsigned* __restrict__ nkeys,
                       const unsigned* __restrict__ hist1,
                       const unsigned* __restrict__ pos,
                       const unsigned* __restrict__ negc,
                       unsigned* __restrict__ hist2,
                       unsigned* __restrict__ b1g,
                       unsigned* __restrict__ rem1g,
                       unsigned* __restrict__ fbg) {
    const int n = blockIdx.y;
    const int tid = threadIdx.x;
    __shared__ unsigned stage[NB1];
    __shared__ unsigned chunk[256];
    __shared__ unsigned h[4][NB2];
    __shared__ unsigned s_b1, s_rem1, s_fb;
    const unsigned* g1 = hist1 + (size_t)n * NB1;
    for (int i = tid; i < NB1; i += 256) stage[i] = g1[i];
    __syncthreads();
    unsigned cs = 0;
#pragma unroll
    for (int j = 0; j < 8; j++) cs += stage[tid * 8 + j];
    chunk[tid] = cs;
    __syncthreads();
    if (tid == 0) {
        const unsigned P = pos[n], NC = negc[n];
        const unsigned nn = (P * 3u < NC) ? P * 3u : NC;
        if (P == 0 || nn == 0) { s_fb = 1u; s_b1 = SENT; s_rem1 = 0; }
        else {
            s_fb = 0u;
            unsigned cum = 0; int c;
            for (c = 255;; c--) { if (cum + chunk[c] >= nn) break; cum += chunk[c]; }
            int bb;
            for (bb = c * 8 + 7;; bb--) { unsigned hv = stage[bb]; if (cum + hv >= nn) break; cum += hv; }
            s_b1 = (unsigned)bb; s_rem1 = nn - cum;
        }
    }
    __syncthreads();
    if (blockIdx.x == 0 && tid == 0) {
        b1g[n] = s_b1; rem1g[n] = s_rem1; fbg[n] = s_fb;
    }
    if (s_fb) return;
    const unsigned B1 = s_b1;
    for (int i = tid; i < 4 * NB2; i += 256) ((unsigned*)h)[i] = 0;
    __syncthreads();
    const int wave = tid >> 6;
    const unsigned nk = nkeys[n];
    const unsigned* kin = keys + (size_t)n * HW;
    for (unsigned i = blockIdx.x * 256 + tid; i < nk; i += BPSC * 256) {
        unsigned key = kin[i];
        if ((key >> L1SHIFT) == B1)
            atomicAdd(&h[wave][(key >> 10) & 0x7FFu], 1u);
    }
    __syncthreads();
    unsigned* g2 = hist2 + (size_t)n * NB2;
    for (int b = tid; b < NB2; b += 256) {
        unsigned s = h[0][b] + h[1][b] + h[2][b] + h[3][b];
        if (s) atomicAdd(&g2[b], s);
    }
}

// Pass 3: recompute scan2 from hist2 (reads rem1g), histogram level-3 into hist3.
__global__ void k_ref3(const unsigned* __restrict__ keys,
                       const unsigned* __restrict__ nkeys,
                       const unsigned* __restrict__ hist2,
                       const unsigned* __restrict__ b1g,
                       const unsigned* __restrict__ rem1g,
                       const unsigned* __restrict__ fbg,
                       unsigned* __restrict__ hist3,
                       unsigned* __restrict__ b2g,
                       unsigned* __restrict__ rem2g) {
    const int n = blockIdx.y;
    const int tid = threadIdx.x;
    if (fbg[n]) {
        if (blockIdx.x == 0 && tid == 0) { b2g[n] = 0; rem2g[n] = 0; }
        return;
    }
    __shared__ unsigned stage[NB2];
    __shared__ unsigned chunk[256];
    __shared__ unsigned h[4][NB3];
    __shared__ unsigned s_b2;
    const unsigned* g2 = hist2 + (size_t)n * NB2;
    for (int i = tid; i < NB2; i += 256) stage[i] = g2[i];
    __syncthreads();
    unsigned cs = 0;
#pragma unroll
    for (int j = 0; j < 8; j++) cs += stage[tid * 8 + j];
    chunk[tid] = cs;
    __syncthreads();
    if (tid == 0) {
        const unsigned r = rem1g[n];
        unsigned cum = 0; int c;
        for (c = 255;; c--) { if (cum + chunk[c] >= r) break; cum += chunk[c]; }
        int bb;
        for (bb = c * 8 + 7;; bb--) { unsigned hv = stage[bb]; if (cum + hv >= r) break; cum += hv; }
        s_b2 = (unsigned)bb;
        if (blockIdx.x == 0) { b2g[n] = (unsigned)bb; rem2g[n] = r - cum; }
    }
    __syncthreads();
    const unsigned prefix = (b1g[n] << 11) | s_b2;
    for (int i = tid; i < 4 * NB3; i += 256) ((unsigned*)h)[i] = 0;
    __syncthreads();
    const int wave = tid >> 6;
    const unsigned nk = nkeys[n];
    const unsigned* kin = keys + (size_t)n * HW;
    for (unsigned i = blockIdx.x * 256 + tid; i < nk; i += BPSC * 256) {
        unsigned key = kin[i];
        if ((key >> 10) == prefix)
            atomicAdd(&h[wave][key & 0x3FFu], 1u);
    }
    __syncthreads();
    unsigned* g3 = hist3 + (size_t)n * NB3;
    for (int b = tid; b < NB3; b += 256) {
        unsigned s = h[0][b] + h[1][b] + h[2][b] + h[3][b];
        if (s) atomicAdd(&g3[b], s);
    }
}

// Pass 4: recompute scan3 from hist3 -> thr in-block, then dice partial sums.
__global__ void k_dice(const float* __restrict__ preds,
                       const float* __restrict__ targets,
                       const float* __restrict__ eff,
                       const unsigned* __restrict__ hist3,
                       const unsigned* __restrict__ b1g,
                       const unsigned* __restrict__ b2g,
                       const unsigned* __restrict__ rem2g,
                       const unsigned* __restrict__ fbg,
                       double* __restrict__ partials) {
    const int n = blockIdx.y;
    const int tid = threadIdx.x, wave = tid >> 6, lane = tid & 63;
    __shared__ unsigned stage[NB3];
    __shared__ unsigned chunk[256];
    __shared__ float s_thr;
    __shared__ double dws[24];
    const bool fallback = (fbg[n] != 0);
    if (!fallback) {
        const unsigned* g3 = hist3 + (size_t)n * NB3;
        for (int i = tid; i < NB3; i += 256) stage[i] = g3[i];
        __syncthreads();
        unsigned cs = 0;
#pragma unroll
        for (int j = 0; j < 4; j++) cs += stage[tid * 4 + j];
        chunk[tid] = cs;
        __syncthreads();
        if (tid == 0) {
            const unsigned r = rem2g[n];
            unsigned cum = 0; int c;
            for (c = 255;; c--) { if (cum + chunk[c] >= r) break; cum += chunk[c]; }
            int bb;
            for (bb = c * 4 + 3;; bb--) { unsigned hv = stage[bb]; if (cum + hv >= r) break; cum += hv; }
            s_thr = inv_sortkey((b1g[n] << L1SHIFT) | (b2g[n] << 10) | (unsigned)bb);
        }
        __syncthreads();
    }
    const float th = fallback ? 0.f : s_thr;
    const float* pr0 = preds + (size_t)n * CPRED * HW;
    const float* tg0 = targets + (size_t)n * 2 * HW;
    const float4* p04 = (const float4*)pr0;
    const float4* p14 = (const float4*)(pr0 + HW);
    const float4* t04 = (const float4*)tg0;
    const float4* t14 = (const float4*)(tg0 + HW);
    const float4* e4  = (const float4*)(eff + (size_t)n * HW);
    float sPG = 0.f, sP2 = 0.f, sG2 = 0.f, sPGk = 0.f, sP2k = 0.f, sG2k = 0.f;
    const int base = blockIdx.x * 1024;
#pragma unroll
    for (int k = 0; k < 4; k++) {
        int i = base + k * 256 + tid;
        float4 a = p04[i], c4 = p14[i], t = t04[i], u = t14[i], e = e4[i];
        float pa[4] = {a.x, a.y, a.z, a.w};
        float pb[4] = {c4.x, c4.y, c4.z, c4.w};
        float ta[4] = {t.x, t.y, t.z, t.w};
        float ua[4] = {u.x, u.y, u.z, u.w};
        float ea[4] = {e.x, e.y, e.z, e.w};
#pragma unroll
        for (int j = 0; j < 4; j++) {
            float pt = sigmoidf(pa[j]);
            float pk = sigmoidf(pb[j]);
            float tbt = (ta[j] > 0.5f) ? 1.f : 0.f;
            float tbk = (ua[j] > 0.5f) ? 1.f : 0.f;
            float m;
            if (fallback) m = ea[j];
            else m = (((pa[j] >= th) || (ta[j] > 0.5f)) && (ea[j] > 0.5f)) ? 1.f : 0.f;
            float Pm = pt * m, Tm = tbt * m;
            sPG += Pm * Tm; sP2 += Pm * Pm; sG2 += Tm * Tm;
            float mk = (pt > 0.5f && ea[j] > 0.5f) ? 1.f : 0.f;
            float Pk = pk * mk, Tk = tbk * mk;
            sPGk += Pk * Tk; sP2k += Pk * Pk; sG2k += Tk * Tk;
        }
    }
    for (int o = 32; o; o >>= 1) {
        sPG  += __shfl_down(sPG, o, 64);
        sP2  += __shfl_down(sP2, o, 64);
        sG2  += __shfl_down(sG2, o, 64);
        sPGk += __shfl_down(sPGk, o, 64);
        sP2k += __shfl_down(sP2k, o, 64);
        sG2k += __shfl_down(sG2k, o, 64);
    }
    __syncthreads();
    if (lane == 0) {
        dws[wave * 6 + 0] = sPG;  dws[wave * 6 + 1] = sP2;  dws[wave * 6 + 2] = sG2;
        dws[wave * 6 + 3] = sPGk; dws[wave * 6 + 4] = sP2k; dws[wave * 6 + 5] = sG2k;
    }
    __syncthreads();
    if (tid < 6) {
        double v = dws[tid] + dws[6 + tid] + dws[12 + tid] + dws[18 + tid];
        partials[((size_t)n * BPSD + blockIdx.x) * 6 + tid] = v;
    }
}

__global__ void k_final(const double* __restrict__ partials, float* __restrict__ out) {
    __shared__ double ssum[96];
    const int t = threadIdx.x;
    if (t < 96) {
        const int n = t / 6, c = t % 6;
        double a = 0.0;
        for (int b = 0; b < BPSD; b++) a += partials[((size_t)n * BPSD + b) * 6 + c];
        ssum[t] = a;
    }
    __syncthreads();
    if (t < NSAMP) {
        const double* s = &ssum[t * 6];
        out[t]         = (float)(1.0 - 2.0 * s[0] / (s[1] + s[2] + EPS));
        out[NSAMP + t] = (float)(1.0 - 2.0 * s[3] / (s[4] + s[5] + EPS));
    }
}

extern "C" void kernel_launch(void* const* d_in, const int* in_sizes, int n_in,
                              void* d_out, int out_size, void* d_ws, size_t ws_size,
                              hipStream_t stream) {
    const float* preds = (const float*)d_in[0];
    const float* targets = (const float*)d_in[1];
    const float* eff = (const float*)d_in[2];
    float* out = (float*)d_out;

    char* ws = (char*)d_ws;
    unsigned* hist1 = (unsigned*)ws;                         // 131072 B
    unsigned* hist2 = (unsigned*)(ws + 131072);              // 131072 B
    unsigned* hist3 = (unsigned*)(ws + 262144);              // 65536 B
    unsigned* pos   = (unsigned*)(ws + 327680);              // counters: 512 B
    unsigned* negc  = pos + NSAMP;
    unsigned* nkeys = negc + NSAMP;
    unsigned* b1g   = nkeys + NSAMP;
    unsigned* rem1g = b1g + NSAMP;
    unsigned* fbg   = rem1g + NSAMP;
    unsigned* b2g   = fbg + NSAMP;
    unsigned* rem2g = b2g + NSAMP;
    double* partials = (double*)(ws + 328192);               // 76800 B
    unsigned* keys  = (unsigned*)(ws + 405504);              // 26.2 MB

    // zero hist1/2/3 + counters (contiguous 328192 B = 20512 uint4)
    k_zero<<<(20512 + 255) / 256, 256, 0, stream>>>((uint4*)ws, 20512);

    dim3 bh(BPSH, NSAMP);
    dim3 bc(BPSC, NSAMP);
    dim3 bd(BPSD, NSAMP);
    k_stats<<<bh, 256, 0, stream>>>(preds, targets, eff, hist1, pos, negc, nkeys, keys);
    k_ref2 <<<bc, 256, 0, stream>>>(keys, nkeys, hist1, pos, negc, hist2, b1g, rem1g, fbg);
    k_ref3 <<<bc, 256, 0, stream>>>(keys, nkeys, hist2, b1g, rem1g, fbg, hist3, b2g, rem2g);
    k_dice <<<bd, 256, 0, stream>>>(preds, targets, eff, hist3, b1g, b2g, rem2g, fbg, partials);
    k_final<<<1, 128, 0, stream>>>(partials, out);
}

// Round 11
// 136.675 us; speedup vs baseline: 6.3592x; 1.0223x over previous
//
#include <hip/hip_runtime.h>
#include <cstddef>

#define NSAMP 16
#define HW 409600
#define CPRED 6
#define EPS 1e-6
#define NB1 2048      // top-11 bits
#define NB2 2048      // next-11 bits
#define NB3 1024      // low-10 bits
#define L1SHIFT 21
#define BPSH 50       // blocks/sample, streaming passes (50 blocks * 8192 elems)
#define BPSD 100      // blocks/sample, dice pass
#define SENT 0xFFFFFFFFu

__device__ __forceinline__ unsigned sortkey(float f) {
    unsigned b = __float_as_uint(f);
    return (b & 0x80000000u) ? ~b : (b | 0x80000000u);   // larger float -> larger key
}
__device__ __forceinline__ float inv_sortkey(unsigned k) {
    unsigned b = (k & 0x80000000u) ? (k ^ 0x80000000u) : ~k;
    return __uint_as_float(b);
}
__device__ __forceinline__ float sigmoidf(float x) {
    return 1.0f / (1.0f + __expf(-x));
}

__global__ void k_zero(uint4* __restrict__ p, unsigned n4) {
    unsigned i = blockIdx.x * 256 + threadIdx.x;
    if (i < n4) p[i] = uint4{0, 0, 0, 0};
}

// Pass 1: stream pred0/t0/eff -> pos/neg counts + level-1 hist.
// 32KB LDS (4 per-wave hist copies for the exponent-concentrated level-1 bins);
// no key compaction (L3 holds all planes; refines re-read instead).
__global__ void k_stats(const float* __restrict__ preds,
                        const float* __restrict__ targets,
                        const float* __restrict__ eff,
                        unsigned* __restrict__ hist1,
                        unsigned* __restrict__ pos,
                        unsigned* __restrict__ negc) {
    const int n = blockIdx.y;
    const float4* p4 = (const float4*)(preds + (size_t)n * CPRED * HW);
    const float4* t4 = (const float4*)(targets + (size_t)n * 2 * HW);
    const float4* e4 = (const float4*)(eff + (size_t)n * HW);
    __shared__ unsigned h[4][NB1];     // 32 KB
    for (int i = threadIdx.x; i < 4 * NB1; i += 256) ((unsigned*)h)[i] = 0;
    __syncthreads();
    const int wave = threadIdx.x >> 6;
    const int lane = threadIdx.x & 63;
    unsigned lp = 0, ln = 0;
    const int base = blockIdx.x * 2048;   // float4 units; 8192 floats/block
#pragma unroll
    for (int k = 0; k < 8; k++) {
        int i = base + k * 256 + threadIdx.x;
        float4 p = p4[i], t = t4[i], e = e4[i];
        float pa[4] = {p.x, p.y, p.z, p.w};
        float ta[4] = {t.x, t.y, t.z, t.w};
        float ea[4] = {e.x, e.y, e.z, e.w};
#pragma unroll
        for (int j = 0; j < 4; j++) {
            lp += (ta[j] > 0.5f && ea[j] > 0.5f) ? 1u : 0u;
            if (ta[j] <= 0.5f) {
                ln++;
                atomicAdd(&h[wave][sortkey(pa[j]) >> L1SHIFT], 1u);
            }
        }
    }
    for (int o = 32; o; o >>= 1) {
        lp += __shfl_down(lp, o, 64);
        ln += __shfl_down(ln, o, 64);
    }
    if (lane == 0) {
        atomicAdd(&pos[n], lp);
        atomicAdd(&negc[n], ln);
    }
    __syncthreads();
    unsigned* gh = hist1 + (size_t)n * NB1;
    for (int b = threadIdx.x; b < NB1; b += 256) {
        unsigned s = h[0][b] + h[1][b] + h[2][b] + h[3][b];
        if (s) atomicAdd(&gh[b], s);
    }
}

// Pass 2: in-block scan1 (redundant per block, ~1us) -> b1/rem1/fb; then
// level-2 histogram by re-reading pred0/t0 (L3-hot). Single hist copy:
// level-2 bins are mantissa-driven (~uniform) -> negligible contention.
__global__ void k_ref2(const float* __restrict__ preds,
                       const float* __restrict__ targets,
                       const unsigned* __restrict__ hist1,
                       const unsigned* __restrict__ pos,
                       const unsigned* __restrict__ negc,
                       unsigned* __restrict__ hist2,
                       unsigned* __restrict__ b1g,
                       unsigned* __restrict__ rem1g,
                       unsigned* __restrict__ fbg) {
    const int n = blockIdx.y;
    const int tid = threadIdx.x;
    __shared__ unsigned stage[NB1];
    __shared__ unsigned chunk[256];
    __shared__ unsigned h[NB2];
    __shared__ unsigned s_b1, s_rem1, s_fb;
    const unsigned* g1 = hist1 + (size_t)n * NB1;
    for (int i = tid; i < NB1; i += 256) stage[i] = g1[i];
    __syncthreads();
    unsigned cs = 0;
#pragma unroll
    for (int j = 0; j < 8; j++) cs += stage[tid * 8 + j];
    chunk[tid] = cs;
    __syncthreads();
    if (tid == 0) {
        const unsigned P = pos[n], NC = negc[n];
        const unsigned nn = (P * 3u < NC) ? P * 3u : NC;
        if (P == 0 || nn == 0) { s_fb = 1u; s_b1 = SENT; s_rem1 = 0; }
        else {
            s_fb = 0u;
            unsigned cum = 0; int c;
            for (c = 255;; c--) { if (cum + chunk[c] >= nn) break; cum += chunk[c]; }
            int bb;
            for (bb = c * 8 + 7;; bb--) { unsigned hv = stage[bb]; if (cum + hv >= nn) break; cum += hv; }
            s_b1 = (unsigned)bb; s_rem1 = nn - cum;
        }
    }
    __syncthreads();
    if (blockIdx.x == 0 && tid == 0) {
        b1g[n] = s_b1; rem1g[n] = s_rem1; fbg[n] = s_fb;
    }
    if (s_fb) return;
    const unsigned B1 = s_b1;
    for (int i = tid; i < NB2; i += 256) h[i] = 0;
    __syncthreads();
    const float4* p4 = (const float4*)(preds + (size_t)n * CPRED * HW);
    const float4* t4 = (const float4*)(targets + (size_t)n * 2 * HW);
    const int base = blockIdx.x * 2048;
#pragma unroll
    for (int k = 0; k < 8; k++) {
        int i = base + k * 256 + tid;
        float4 p = p4[i], t = t4[i];
        float pa[4] = {p.x, p.y, p.z, p.w};
        float ta[4] = {t.x, t.y, t.z, t.w};
#pragma unroll
        for (int j = 0; j < 4; j++) {
            if (ta[j] <= 0.5f) {
                unsigned key = sortkey(pa[j]);
                if ((key >> L1SHIFT) == B1)
                    atomicAdd(&h[(key >> 10) & 0x7FFu], 1u);
            }
        }
    }
    __syncthreads();
    unsigned* g2 = hist2 + (size_t)n * NB2;
    for (int b = tid; b < NB2; b += 256) {
        unsigned v = h[b];
        if (v) atomicAdd(&g2[b], v);
    }
}

// Pass 3: in-block scan2 -> b2/rem2; level-3 histogram (re-read, L3-hot).
__global__ void k_ref3(const float* __restrict__ preds,
                       const float* __restrict__ targets,
                       const unsigned* __restrict__ hist2,
                       const unsigned* __restrict__ b1g,
                       const unsigned* __restrict__ rem1g,
                       const unsigned* __restrict__ fbg,
                       unsigned* __restrict__ hist3,
                       unsigned* __restrict__ b2g,
                       unsigned* __restrict__ rem2g) {
    const int n = blockIdx.y;
    const int tid = threadIdx.x;
    if (fbg[n]) {
        if (blockIdx.x == 0 && tid == 0) { b2g[n] = 0; rem2g[n] = 0; }
        return;
    }
    __shared__ unsigned stage[NB2];
    __shared__ unsigned chunk[256];
    __shared__ unsigned h[NB3];
    __shared__ unsigned s_b2;
    const unsigned* g2 = hist2 + (size_t)n * NB2;
    for (int i = tid; i < NB2; i += 256) stage[i] = g2[i];
    __syncthreads();
    unsigned cs = 0;
#pragma unroll
    for (int j = 0; j < 8; j++) cs += stage[tid * 8 + j];
    chunk[tid] = cs;
    __syncthreads();
    if (tid == 0) {
        const unsigned r = rem1g[n];
        unsigned cum = 0; int c;
        for (c = 255;; c--) { if (cum + chunk[c] >= r) break; cum += chunk[c]; }
        int bb;
        for (bb = c * 8 + 7;; bb--) { unsigned hv = stage[bb]; if (cum + hv >= r) break; cum += hv; }
        s_b2 = (unsigned)bb;
        if (blockIdx.x == 0) { b2g[n] = (unsigned)bb; rem2g[n] = r - cum; }
    }
    __syncthreads();
    const unsigned prefix = (b1g[n] << 11) | s_b2;
    for (int i = tid; i < NB3; i += 256) h[i] = 0;
    __syncthreads();
    const float4* p4 = (const float4*)(preds + (size_t)n * CPRED * HW);
    const float4* t4 = (const float4*)(targets + (size_t)n * 2 * HW);
    const int base = blockIdx.x * 2048;
#pragma unroll
    for (int k = 0; k < 8; k++) {
        int i = base + k * 256 + tid;
        float4 p = p4[i], t = t4[i];
        float pa[4] = {p.x, p.y, p.z, p.w};
        float ta[4] = {t.x, t.y, t.z, t.w};
#pragma unroll
        for (int j = 0; j < 4; j++) {
            if (ta[j] <= 0.5f) {
                unsigned key = sortkey(pa[j]);
                if ((key >> 10) == prefix)
                    atomicAdd(&h[key & 0x3FFu], 1u);
            }
        }
    }
    __syncthreads();
    unsigned* g3 = hist3 + (size_t)n * NB3;
    for (int b = tid; b < NB3; b += 256) {
        unsigned v = h[b];
        if (v) atomicAdd(&g3[b], v);
    }
}

// Pass 4: in-block scan3 -> thr, then dice partial sums (plain store per block).
__global__ void k_dice(const float* __restrict__ preds,
                       const float* __restrict__ targets,
                       const float* __restrict__ eff,
                       const unsigned* __restrict__ hist3,
                       const unsigned* __restrict__ b1g,
                       const unsigned* __restrict__ b2g,
                       const unsigned* __restrict__ rem2g,
                       const unsigned* __restrict__ fbg,
                       double* __restrict__ partials) {
    const int n = blockIdx.y;
    const int tid = threadIdx.x, wave = tid >> 6, lane = tid & 63;
    __shared__ unsigned stage[NB3];
    __shared__ unsigned chunk[256];
    __shared__ float s_thr;
    __shared__ double dws[24];
    const bool fallback = (fbg[n] != 0);
    if (!fallback) {
        const unsigned* g3 = hist3 + (size_t)n * NB3;
        for (int i = tid; i < NB3; i += 256) stage[i] = g3[i];
        __syncthreads();
        unsigned cs = 0;
#pragma unroll
        for (int j = 0; j < 4; j++) cs += stage[tid * 4 + j];
        chunk[tid] = cs;
        __syncthreads();
        if (tid == 0) {
            const unsigned r = rem2g[n];
            unsigned cum = 0; int c;
            for (c = 255;; c--) { if (cum + chunk[c] >= r) break; cum += chunk[c]; }
            int bb;
            for (bb = c * 4 + 3;; bb--) { unsigned hv = stage[bb]; if (cum + hv >= r) break; cum += hv; }
            s_thr = inv_sortkey((b1g[n] << L1SHIFT) | (b2g[n] << 10) | (unsigned)bb);
        }
        __syncthreads();
    }
    const float th = fallback ? 0.f : s_thr;
    const float* pr0 = preds + (size_t)n * CPRED * HW;
    const float* tg0 = targets + (size_t)n * 2 * HW;
    const float4* p04 = (const float4*)pr0;
    const float4* p14 = (const float4*)(pr0 + HW);
    const float4* t04 = (const float4*)tg0;
    const float4* t14 = (const float4*)(tg0 + HW);
    const float4* e4  = (const float4*)(eff + (size_t)n * HW);
    float sPG = 0.f, sP2 = 0.f, sG2 = 0.f, sPGk = 0.f, sP2k = 0.f, sG2k = 0.f;
    const int base = blockIdx.x * 1024;
#pragma unroll
    for (int k = 0; k < 4; k++) {
        int i = base + k * 256 + tid;
        float4 a = p04[i], c4 = p14[i], t = t04[i], u = t14[i], e = e4[i];
        float pa[4] = {a.x, a.y, a.z, a.w};
        float pb[4] = {c4.x, c4.y, c4.z, c4.w};
        float ta[4] = {t.x, t.y, t.z, t.w};
        float ua[4] = {u.x, u.y, u.z, u.w};
        float ea[4] = {e.x, e.y, e.z, e.w};
#pragma unroll
        for (int j = 0; j < 4; j++) {
            float pt = sigmoidf(pa[j]);
            float pk = sigmoidf(pb[j]);
            float tbt = (ta[j] > 0.5f) ? 1.f : 0.f;
            float tbk = (ua[j] > 0.5f) ? 1.f : 0.f;
            float m;
            if (fallback) m = ea[j];
            else m = (((pa[j] >= th) || (ta[j] > 0.5f)) && (ea[j] > 0.5f)) ? 1.f : 0.f;
            float Pm = pt * m, Tm = tbt * m;
            sPG += Pm * Tm; sP2 += Pm * Pm; sG2 += Tm * Tm;
            float mk = (pt > 0.5f && ea[j] > 0.5f) ? 1.f : 0.f;
            float Pk = pk * mk, Tk = tbk * mk;
            sPGk += Pk * Tk; sP2k += Pk * Pk; sG2k += Tk * Tk;
        }
    }
    for (int o = 32; o; o >>= 1) {
        sPG  += __shfl_down(sPG, o, 64);
        sP2  += __shfl_down(sP2, o, 64);
        sG2  += __shfl_down(sG2, o, 64);
        sPGk += __shfl_down(sPGk, o, 64);
        sP2k += __shfl_down(sP2k, o, 64);
        sG2k += __shfl_down(sG2k, o, 64);
    }
    __syncthreads();
    if (lane == 0) {
        dws[wave * 6 + 0] = sPG;  dws[wave * 6 + 1] = sP2;  dws[wave * 6 + 2] = sG2;
        dws[wave * 6 + 3] = sPGk; dws[wave * 6 + 4] = sP2k; dws[wave * 6 + 5] = sG2k;
    }
    __syncthreads();
    if (tid < 6) {
        double v = dws[tid] + dws[6 + tid] + dws[12 + tid] + dws[18 + tid];
        partials[((size_t)n * BPSD + blockIdx.x) * 6 + tid] = v;
    }
}

__global__ void k_final(const double* __restrict__ partials, float* __restrict__ out) {
    __shared__ double ssum[96];
    const int t = threadIdx.x;
    if (t < 96) {
        const int n = t / 6, c = t % 6;
        double a = 0.0;
        for (int b = 0; b < BPSD; b++) a += partials[((size_t)n * BPSD + b) * 6 + c];
        ssum[t] = a;
    }
    __syncthreads();
    if (t < NSAMP) {
        const double* s = &ssum[t * 6];
        out[t]         = (float)(1.0 - 2.0 * s[0] / (s[1] + s[2] + EPS));
        out[NSAMP + t] = (float)(1.0 - 2.0 * s[3] / (s[4] + s[5] + EPS));
    }
}

extern "C" void kernel_launch(void* const* d_in, const int* in_sizes, int n_in,
                              void* d_out, int out_size, void* d_ws, size_t ws_size,
                              hipStream_t stream) {
    const float* preds = (const float*)d_in[0];
    const float* targets = (const float*)d_in[1];
    const float* eff = (const float*)d_in[2];
    float* out = (float*)d_out;

    char* ws = (char*)d_ws;
    unsigned* hist1 = (unsigned*)ws;                         // 131072 B
    unsigned* hist2 = (unsigned*)(ws + 131072);              // 131072 B
    unsigned* hist3 = (unsigned*)(ws + 262144);              // 65536 B
    unsigned* pos   = (unsigned*)(ws + 327680);              // counters: 512 B
    unsigned* negc  = pos + NSAMP;
    unsigned* b1g   = negc + NSAMP;
    unsigned* rem1g = b1g + NSAMP;
    unsigned* fbg   = rem1g + NSAMP;
    unsigned* b2g   = fbg + NSAMP;
    unsigned* rem2g = b2g + NSAMP;
    double* partials = (double*)(ws + 328192);               // 76800 B

    // zero hist1/2/3 + counters (contiguous 328192 B = 20512 uint4)
    k_zero<<<(20512 + 255) / 256, 256, 0, stream>>>((uint4*)ws, 20512);

    dim3 bh(BPSH, NSAMP);
    dim3 bd(BPSD, NSAMP);
    k_stats<<<bh, 256, 0, stream>>>(preds, targets, eff, hist1, pos, negc);
    k_ref2 <<<bh, 256, 0, stream>>>(preds, targets, hist1, pos, negc, hist2, b1g, rem1g, fbg);
    k_ref3 <<<bh, 256, 0, stream>>>(preds, targets, hist2, b1g, rem1g, fbg, hist3, b2g, rem2g);
    k_dice <<<bd, 256, 0, stream>>>(preds, targets, eff, hist3, b1g, b2g, rem2g, fbg, partials);
    k_final<<<1, 128, 0, stream>>>(partials, out);
}

// Round 12
// 60.267 us; speedup vs baseline: 14.4217x; 2.2678x over previous
//
#include <hip/hip_runtime.h>
#include <cstddef>

#define NSAMP 16
#define HW 409600
#define CPRED 6
#define EPS 1e-6
#define BPS1 50        // blocks/sample, streaming passes (50 * 8192 = 409600)
#define BPSD 100       // blocks/sample, dice
#define NBA 64         // level-1 bins (top 6 bits)
#define SH1 26
#define NBB 8192       // level-2/3 bins (13 bits each)
#define REG 8192       // per-block key region (block max elements)

__device__ __forceinline__ unsigned sortkey(float f) {
    unsigned b = __float_as_uint(f);
    return (b & 0x80000000u) ? ~b : (b | 0x80000000u);   // larger float -> larger key
}
__device__ __forceinline__ float inv_sortkey(unsigned k) {
    unsigned b = (k & 0x80000000u) ? (k ^ 0x80000000u) : ~k;
    return __uint_as_float(b);
}
__device__ __forceinline__ float sigmoidf(float x) {
    return 1.0f / (1.0f + __expf(-x));
}

// Pass 1: stream p0/t0/eff. Per-block PLAIN stores (no zeroing, no global
// atomics): pos, neg, max(~key) over negatives, 64-bin top-6 histogram.
__global__ void k_pass1(const float* __restrict__ preds,
                        const float* __restrict__ targets,
                        const float* __restrict__ eff,
                        unsigned* __restrict__ histP,   // [16][50][64]
                        unsigned* __restrict__ posP,    // [16][50]
                        unsigned* __restrict__ negP,
                        unsigned* __restrict__ nkP) {   // max of ~key
    const int n = blockIdx.y, x = blockIdx.x;
    const int tid = threadIdx.x, wave = tid >> 6, lane = tid & 63;
    __shared__ unsigned h[4][NBA];
    __shared__ unsigned wred[12];
    ((unsigned*)h)[tid] = 0;           // 4*64 == 256
    __syncthreads();
    const float4* p4 = (const float4*)(preds + (size_t)n * CPRED * HW);
    const float4* t4 = (const float4*)(targets + (size_t)n * 2 * HW);
    const float4* e4 = (const float4*)(eff + (size_t)n * HW);
    const int base = x * 2048;
    unsigned lp = 0, ln = 0, mx = 0;
#pragma unroll
    for (int k = 0; k < 8; k++) {
        int i = base + k * 256 + tid;
        float4 p = p4[i], t = t4[i], e = e4[i];
        float pa[4] = {p.x, p.y, p.z, p.w};
        float ta[4] = {t.x, t.y, t.z, t.w};
        float ea[4] = {e.x, e.y, e.z, e.w};
#pragma unroll
        for (int j = 0; j < 4; j++) {
            lp += (ta[j] > 0.5f && ea[j] > 0.5f) ? 1u : 0u;
            if (ta[j] <= 0.5f) {
                ln++;
                unsigned key = sortkey(pa[j]);
                atomicAdd(&h[wave][key >> SH1], 1u);
                unsigned nk = ~key;
                mx = (nk > mx) ? nk : mx;
            }
        }
    }
    for (int o = 32; o; o >>= 1) {
        lp += __shfl_down(lp, o, 64);
        ln += __shfl_down(ln, o, 64);
        unsigned om = __shfl_down(mx, o, 64);
        mx = (om > mx) ? om : mx;
    }
    if (lane == 0) { wred[wave] = lp; wred[4 + wave] = ln; wred[8 + wave] = mx; }
    __syncthreads();
    const int bi = n * BPS1 + x;
    if (tid == 0) {
        posP[bi] = wred[0] + wred[1] + wred[2] + wred[3];
        negP[bi] = wred[4] + wred[5] + wred[6] + wred[7];
        unsigned m = wred[8];
        m = (wred[9] > m) ? wred[9] : m;
        m = (wred[10] > m) ? wred[10] : m;
        m = (wred[11] > m) ? wred[11] : m;
        nkP[bi] = m;
    }
    if (tid < NBA)
        histP[(size_t)bi * NBA + tid] = h[0][tid] + h[1][tid] + h[2][tid] + h[3][tid];
}

// Pass 2 (general path only): each block recomputes nn/need + b1 from the tiny
// partials, early-exits when the shortcut applies (this benchmark: always).
// Else compacts bucket-b1 negatives' keys into its OWN region (no atomics).
__global__ void k_ref2c(const float* __restrict__ preds,
                        const float* __restrict__ targets,
                        const unsigned* __restrict__ posP,
                        const unsigned* __restrict__ negP,
                        const unsigned* __restrict__ histP,
                        unsigned* __restrict__ keys,    // [16][50][8192]
                        unsigned* __restrict__ cntP) {  // [16][50]
    const int n = blockIdx.y, x = blockIdx.x;
    const int tid = threadIdx.x, wave = tid >> 6, lane = tid & 63;
    __shared__ unsigned sP, sN;
    __shared__ unsigned hsum[NBA];
    __shared__ int s_need;
    __shared__ unsigned s_b1;
    __shared__ unsigned kbuf[4][2048];
    __shared__ unsigned kcnt[4];
    if (tid == 0) { sP = 0; sN = 0; }
    __syncthreads();
    if (tid < BPS1) {
        atomicAdd(&sP, posP[n * BPS1 + tid]);
        atomicAdd(&sN, negP[n * BPS1 + tid]);
    }
    if (tid < NBA) {
        unsigned s = 0;
        for (int xx = 0; xx < BPS1; xx++) s += histP[(size_t)(n * BPS1 + xx) * NBA + tid];
        hsum[tid] = s;
    }
    __syncthreads();
    if (tid == 0) {
        const unsigned P = sP, NC = sN;
        const unsigned nn = (P * 3u < NC) ? P * 3u : NC;
        const bool need = (P > 0 && nn > 0 && nn < NC);
        s_need = need ? 1 : 0;
        if (need) {
            unsigned cum = 0; int b;
            for (b = NBA - 1;; b--) { if (cum + hsum[b] >= nn) break; cum += hsum[b]; }
            s_b1 = (unsigned)b;
        }
    }
    __syncthreads();
    if (!s_need) {
        if (tid == 0) cntP[n * BPS1 + x] = 0;
        return;
    }
    const unsigned B1 = s_b1;
    const float4* p4 = (const float4*)(preds + (size_t)n * CPRED * HW);
    const float4* t4 = (const float4*)(targets + (size_t)n * 2 * HW);
    const unsigned long long lmask = (1ull << lane) - 1ull;
    unsigned run = 0;
    const int base = x * 2048;
#pragma unroll
    for (int k = 0; k < 8; k++) {
        int i = base + k * 256 + tid;
        float4 p = p4[i], t = t4[i];
        float pa[4] = {p.x, p.y, p.z, p.w};
        float ta[4] = {t.x, t.y, t.z, t.w};
#pragma unroll
        for (int j = 0; j < 4; j++) {
            unsigned key = sortkey(pa[j]);
            const bool m = (ta[j] <= 0.5f) && ((key >> SH1) == B1);
            unsigned long long bm = __ballot(m);
            if (m) {
                int rank = __popcll(bm & lmask);
                kbuf[wave][run + rank] = key;
            }
            run += (unsigned)__popcll(bm);
        }
    }
    if (lane == 0) kcnt[wave] = run;
    __syncthreads();
    unsigned off = 0;
    for (int w = 0; w < wave; w++) off += kcnt[w];
    if (tid == 0) cntP[n * BPS1 + x] = kcnt[0] + kcnt[1] + kcnt[2] + kcnt[3];
    unsigned* kout = keys + (size_t)(n * BPS1 + x) * REG;
    const unsigned cnt = kcnt[wave];
    for (unsigned i = lane; i < cnt; i += 64) kout[off + i] = kbuf[wave][i];
}

// Pass 3: one block per sample. Shortcut thr = min negative (from ~key max);
// general path: exact 13+13-bit select over the compacted bucket values.
__global__ void k_sel(const unsigned* __restrict__ posP,
                      const unsigned* __restrict__ negP,
                      const unsigned* __restrict__ nkP,
                      const unsigned* __restrict__ histP,
                      const unsigned* __restrict__ keys,
                      const unsigned* __restrict__ cntP,
                      float* __restrict__ thrg,
                      unsigned* __restrict__ fbg) {
    const int n = blockIdx.x;
    const int tid = threadIdx.x;
    __shared__ unsigned hist[NBB];      // 32 KB
    __shared__ unsigned chunk[256];
    __shared__ unsigned sP, sN, sMX;
    __shared__ int s_need;
    __shared__ unsigned s_b1, s_rem1, s_b2, s_rem2;
    if (tid == 0) { sP = 0; sN = 0; sMX = 0; }
    __syncthreads();
    if (tid < BPS1) {
        atomicAdd(&sP, posP[n * BPS1 + tid]);
        atomicAdd(&sN, negP[n * BPS1 + tid]);
        atomicMax(&sMX, nkP[n * BPS1 + tid]);
    }
    if (tid < NBA) {
        unsigned s = 0;
        for (int xx = 0; xx < BPS1; xx++) s += histP[(size_t)(n * BPS1 + xx) * NBA + tid];
        hist[tid] = s;
    }
    __syncthreads();
    if (tid == 0) {
        const unsigned P = sP, NC = sN;
        const unsigned nn = (P * 3u < NC) ? P * 3u : NC;
        const bool fb = (P == 0 || nn == 0);
        const bool need = (!fb && nn < NC);
        s_need = need ? 1 : 0;
        if (!need) {
            fbg[n] = fb ? 1u : 0u;
            thrg[n] = fb ? -INFINITY : inv_sortkey(~sMX);
        } else {
            fbg[n] = 0u;
            unsigned cum = 0; int b;
            for (b = NBA - 1;; b--) { if (cum + hist[b] >= nn) break; cum += hist[b]; }
            s_b1 = (unsigned)b; s_rem1 = nn - cum;
        }
    }
    __syncthreads();
    if (!s_need) return;
    // Round A: 13-bit digit (key>>13)&0x1FFF over bucket values
    for (int i = tid; i < NBB; i += 256) hist[i] = 0;
    __syncthreads();
    for (int xx = 0; xx < BPS1; xx++) {
        const unsigned c = cntP[n * BPS1 + xx];
        const unsigned* kin = keys + (size_t)(n * BPS1 + xx) * REG;
        for (unsigned i = tid; i < c; i += 256)
            atomicAdd(&hist[(kin[i] >> 13) & 0x1FFFu], 1u);
    }
    __syncthreads();
    {
        unsigned cs = 0;
#pragma unroll
        for (int j = 0; j < 32; j++) cs += hist[tid * 32 + j];
        chunk[tid] = cs;
    }
    __syncthreads();
    if (tid == 0) {
        const unsigned r = s_rem1;
        unsigned cum = 0; int c;
        for (c = 255;; c--) { if (cum + chunk[c] >= r) break; cum += chunk[c]; }
        int b;
        for (b = c * 32 + 31;; b--) { unsigned hv = hist[b]; if (cum + hv >= r) break; cum += hv; }
        s_b2 = (unsigned)b; s_rem2 = r - cum;
    }
    __syncthreads();
    const unsigned B2 = s_b2;
    // Round B: low 13 bits among values with digit == B2
    for (int i = tid; i < NBB; i += 256) hist[i] = 0;
    __syncthreads();
    for (int xx = 0; xx < BPS1; xx++) {
        const unsigned c = cntP[n * BPS1 + xx];
        const unsigned* kin = keys + (size_t)(n * BPS1 + xx) * REG;
        for (unsigned i = tid; i < c; i += 256) {
            unsigned key = kin[i];
            if (((key >> 13) & 0x1FFFu) == B2) atomicAdd(&hist[key & 0x1FFFu], 1u);
        }
    }
    __syncthreads();
    {
        unsigned cs = 0;
#pragma unroll
        for (int j = 0; j < 32; j++) cs += hist[tid * 32 + j];
        chunk[tid] = cs;
    }
    __syncthreads();
    if (tid == 0) {
        const unsigned r = s_rem2;
        unsigned cum = 0; int c;
        for (c = 255;; c--) { if (cum + chunk[c] >= r) break; cum += chunk[c]; }
        int b;
        for (b = c * 32 + 31;; b--) { unsigned hv = hist[b]; if (cum + hv >= r) break; cum += hv; }
        thrg[n] = inv_sortkey((s_b1 << SH1) | (B2 << 13) | (unsigned)b);
    }
}

// Pass 4: dice partial sums (thr/fb are ready scalars now; no staging).
__global__ void k_dice(const float* __restrict__ preds,
                       const float* __restrict__ targets,
                       const float* __restrict__ eff,
                       const float* __restrict__ thrg,
                       const unsigned* __restrict__ fbg,
                       double* __restrict__ partials) {
    const int n = blockIdx.y;
    const int tid = threadIdx.x, wave = tid >> 6, lane = tid & 63;
    __shared__ double dws[24];
    const float th = thrg[n];
    const bool fallback = (fbg[n] != 0);
    const float* pr0 = preds + (size_t)n * CPRED * HW;
    const float* tg0 = targets + (size_t)n * 2 * HW;
    const float4* p04 = (const float4*)pr0;
    const float4* p14 = (const float4*)(pr0 + HW);
    const float4* t04 = (const float4*)tg0;
    const float4* t14 = (const float4*)(tg0 + HW);
    const float4* e4  = (const float4*)(eff + (size_t)n * HW);
    float sPG = 0.f, sP2 = 0.f, sG2 = 0.f, sPGk = 0.f, sP2k = 0.f, sG2k = 0.f;
    const int base = blockIdx.x * 1024;
#pragma unroll
    for (int k = 0; k < 4; k++) {
        int i = base + k * 256 + tid;
        float4 a = p04[i], c4 = p14[i], t = t04[i], u = t14[i], e = e4[i];
        float pa[4] = {a.x, a.y, a.z, a.w};
        float pb[4] = {c4.x, c4.y, c4.z, c4.w};
        float ta[4] = {t.x, t.y, t.z, t.w};
        float ua[4] = {u.x, u.y, u.z, u.w};
        float ea[4] = {e.x, e.y, e.z, e.w};
#pragma unroll
        for (int j = 0; j < 4; j++) {
            float pt = sigmoidf(pa[j]);
            float pk = sigmoidf(pb[j]);
            float tbt = (ta[j] > 0.5f) ? 1.f : 0.f;
            float tbk = (ua[j] > 0.5f) ? 1.f : 0.f;
            float m;
            if (fallback) m = ea[j];
            else m = (((pa[j] >= th) || (ta[j] > 0.5f)) && (ea[j] > 0.5f)) ? 1.f : 0.f;
            float Pm = pt * m, Tm = tbt * m;
            sPG += Pm * Tm; sP2 += Pm * Pm; sG2 += Tm * Tm;
            float mk = (pt > 0.5f && ea[j] > 0.5f) ? 1.f : 0.f;
            float Pk = pk * mk, Tk = tbk * mk;
            sPGk += Pk * Tk; sP2k += Pk * Pk; sG2k += Tk * Tk;
        }
    }
    for (int o = 32; o; o >>= 1) {
        sPG  += __shfl_down(sPG, o, 64);
        sP2  += __shfl_down(sP2, o, 64);
        sG2  += __shfl_down(sG2, o, 64);
        sPGk += __shfl_down(sPGk, o, 64);
        sP2k += __shfl_down(sP2k, o, 64);
        sG2k += __shfl_down(sG2k, o, 64);
    }
    if (lane == 0) {
        dws[wave * 6 + 0] = sPG;  dws[wave * 6 + 1] = sP2;  dws[wave * 6 + 2] = sG2;
        dws[wave * 6 + 3] = sPGk; dws[wave * 6 + 4] = sP2k; dws[wave * 6 + 5] = sG2k;
    }
    __syncthreads();
    if (tid < 6) {
        double v = dws[tid] + dws[6 + tid] + dws[12 + tid] + dws[18 + tid];
        partials[((size_t)n * BPSD + blockIdx.x) * 6 + tid] = v;
    }
}

__global__ void k_final(const double* __restrict__ partials, float* __restrict__ out) {
    __shared__ double ssum[96];
    const int t = threadIdx.x;
    if (t < 96) {
        const int n = t / 6, c = t % 6;
        double a = 0.0;
        for (int b = 0; b < BPSD; b++) a += partials[((size_t)n * BPSD + b) * 6 + c];
        ssum[t] = a;
    }
    __syncthreads();
    if (t < NSAMP) {
        const double* s = &ssum[t * 6];
        out[t]         = (float)(1.0 - 2.0 * s[0] / (s[1] + s[2] + EPS));
        out[NSAMP + t] = (float)(1.0 - 2.0 * s[3] / (s[4] + s[5] + EPS));
    }
}

extern "C" void kernel_launch(void* const* d_in, const int* in_sizes, int n_in,
                              void* d_out, int out_size, void* d_ws, size_t ws_size,
                              hipStream_t stream) {
    const float* preds = (const float*)d_in[0];
    const float* targets = (const float*)d_in[1];
    const float* eff = (const float*)d_in[2];
    float* out = (float*)d_out;

    // Everything plain-stored each call -> NO zero kernel.
    char* ws = (char*)d_ws;
    unsigned* histP = (unsigned*)ws;                          // 16*50*64*4 = 204800
    unsigned* posP  = (unsigned*)(ws + 204800);               // 800*4
    unsigned* negP  = posP + NSAMP * BPS1;
    unsigned* nkP   = negP + NSAMP * BPS1;
    unsigned* cntP  = nkP + NSAMP * BPS1;                     // ends 217600
    float*    thrg  = (float*)(ws + 217600);
    unsigned* fbg   = (unsigned*)(thrg + NSAMP);              // ends 217728
    double* partials = (double*)(ws + 217728);                // 76800 B
    unsigned* keys  = (unsigned*)(ws + 294528);               // 16*50*8192*4 = 26.2 MB

    dim3 b1(BPS1, NSAMP);
    dim3 bd(BPSD, NSAMP);
    k_pass1<<<b1, 256, 0, stream>>>(preds, targets, eff, histP, posP, negP, nkP);
    k_ref2c<<<b1, 256, 0, stream>>>(preds, targets, posP, negP, histP, keys, cntP);
    k_sel  <<<NSAMP, 256, 0, stream>>>(posP, negP, nkP, histP, keys, cntP, thrg, fbg);
    k_dice <<<bd, 256, 0, stream>>>(preds, targets, eff, thrg, fbg, partials);
    k_final<<<1, 128, 0, stream>>>(partials, out);
}